// Round 3
// baseline (281.347 us; speedup 1.0000x reference)
//
#include <hip/hip_runtime.h>
#include <hip/hip_bf16.h>
#include <math.h>

// Problem constants (fixed by setup_inputs)
#define B_SZ 2
#define N_SEQ 2048
#define DIM 512
#define H_HEADS 8
#define D_HEAD 64
#define K_NN 32
#define M_DB 131072

typedef __attribute__((ext_vector_type(8))) short bf16x8;
typedef __attribute__((ext_vector_type(4))) float f32x4;

// async global->LDS, 16B per lane. LDS dest is wave-uniform base + lane*16;
// global src is per-lane (pre-swizzle the SOURCE, keep LDS linear).
#define GLL16(g, l)                                                       \
    __builtin_amdgcn_global_load_lds(                                     \
        (const __attribute__((address_space(1))) unsigned int*)(g),       \
        (__attribute__((address_space(3))) unsigned int*)(l), 16, 0, 0)

// ---------------------------------------------------------------------------
// fp32 -> (hi, lo) bf16 split. f ~= hi + lo to ~2^-17 relative.
// ---------------------------------------------------------------------------
__device__ __forceinline__ void cvt_hi_lo(float f, short& h, short& l) {
    unsigned u = __float_as_uint(f);
    unsigned uh = u + (0x7fffu + ((u >> 16) & 1u));
    h = (short)(uh >> 16);
    float r = f - __uint_as_float((uh >> 16) << 16);
    unsigned ur = __float_as_uint(r);
    l = (short)((ur + (0x7fffu + ((ur >> 16) & 1u))) >> 16);
}

__device__ __forceinline__ void split4(float4 a, ushort4& h, ushort4& l) {
    short hh, ll;
    cvt_hi_lo(a.x, hh, ll); h.x = hh; l.x = ll;
    cvt_hi_lo(a.y, hh, ll); h.y = hh; l.y = ll;
    cvt_hi_lo(a.z, hh, ll); h.z = hh; l.z = ll;
    cvt_hi_lo(a.w, hh, ll); h.w = hh; l.w = ll;
}

// ---------------------------------------------------------------------------
// Fused prep: split x (2048 blocks) + Wq/Wout (512 blocks) into bf16 hi/lo
// planes, and detect mask layout (1 block). One dispatch.
// ---------------------------------------------------------------------------
__global__ __launch_bounds__(256) void prep_kernel(
    const float4* __restrict__ x, const float4* __restrict__ wq,
    const float4* __restrict__ wout,
    ushort4* __restrict__ xhi, ushort4* __restrict__ xlo,
    ushort4* __restrict__ qhi, ushort4* __restrict__ qlo,
    ushort4* __restrict__ ohi, ushort4* __restrict__ olo,
    const unsigned char* __restrict__ mb, int* __restrict__ flag)
{
    const int bid = blockIdx.x;
    const int t = threadIdx.x;
    if (bid < 2048) {                       // x: 524288 float4s
        int i = bid * 256 + t;
        ushort4 h, l;
        split4(x[i], h, l);
        xhi[i] = h; xlo[i] = l;
    } else if (bid < 2560) {                // weights: 2*65536 float4s
        int i = (bid - 2048) * 256 + t;
        const int n4 = DIM * DIM / 4;       // 65536
        const float4* src = (i < n4) ? wq : wout;
        ushort4* dh = (i < n4) ? qhi : ohi;
        ushort4* dl = (i < n4) ? qlo : olo;
        int j = (i < n4) ? i : i - n4;
        ushort4 h, l;
        split4(src[j], h, l);
        dh[j] = h; dl[j] = l;
    } else {                                // mask-layout detect (64 lanes act)
        if (t < 64) {
            unsigned char v = 0;
            for (int e = t; e < 1024; e += 64) {
                v |= mb[4 * e + 1];
                v |= mb[4 * e + 2];
                v |= mb[4 * e + 3];
            }
            unsigned long long any = __ballot(v != 0);
            if (t == 0) *flag = (any != 0ull) ? 1 : 0;  // 1 = byte layout
        }
    }
}

// ---------------------------------------------------------------------------
// fp32-accurate MFMA GEMM (NT) on pre-split bf16 planes, LDS-STAGED:
// C[m,n] = sum_k A[m,k]*W[n,k], 3 passes (hh + hl + lh) ~= fp32.
//
// Fragment-order staging: global_load_lds writes LDS linearly (base+lane*16),
// so we pre-swizzle the GLOBAL source address so each 1KB chunk lands as one
// MFMA fragment-set. Chunk c (0..15 A, 16..31 B): p=c>>3 (hi/lo plane),
// s=(c>>2)&1 (k-half), h=c&3 (16-row group); lane l stages row 16h+(l&15),
// cols 32s+8*(l>>4)..+7. Compute-side ds_read_b128 = chunk*1024 + lane*16:
// linear, conflict-free, zero in-loop address math.
//
// Tile 64x64, BK=64, dbuf 2x32KB LDS, grid (M/64, N/64) = (64,8) = 2 blk/CU.
// Block: 256 thr = 4 waves; wave = 32x32 out = 2x2 of 16x16x32 mfma.
// A-frag: m=lane&15, k=(lane>>4)*8+j.  C/D: col=lane&15, row=(lane>>4)*4+reg.
// ---------------------------------------------------------------------------
__global__ __launch_bounds__(256) void gemm_mfma_lds(
    const unsigned short* __restrict__ Ahi, const unsigned short* __restrict__ Alo,
    const unsigned short* __restrict__ Bhi, const unsigned short* __restrict__ Blo,
    float* __restrict__ C, int Mdim, int Ndim, int Kdim)
{
    __shared__ char lds[2][32768];
    const int t = threadIdx.x;
    const int w = t >> 6, lane = t & 63;
    const int r = lane & 15, qd = lane >> 4;
    const int wm = w & 1, wn = w >> 1;
    const int m0 = blockIdx.x * 64;
    const int n0 = blockIdx.y * 64;

    // Per-wave staging sources: 8 chunks (c_lin = j*4 + w), kstep-0 addresses.
    const unsigned short* gsrc[8];
#pragma unroll
    for (int j = 0; j < 8; ++j) {
        const int cl = j * 4 + w;
        const int isB = cl >> 4;
        const int c = cl & 15;
        const int p = c >> 3, s = (c >> 2) & 1, h = c & 3;
        const int row = (isB ? n0 : m0) + 16 * h + r;
        const int col = 32 * s + 8 * qd;
        const unsigned short* plane =
            isB ? (p ? Blo : Bhi) : (p ? Alo : Ahi);
        gsrc[j] = plane + (size_t)row * Kdim + col;
    }

    f32x4 acc[2][2];
#pragma unroll
    for (int i = 0; i < 2; ++i)
#pragma unroll
        for (int j = 0; j < 2; ++j) acc[i][j] = (f32x4){0.f, 0.f, 0.f, 0.f};

    auto stage = [&](int buf, int kstep) {
#pragma unroll
        for (int j = 0; j < 8; ++j) {
            const int cl = j * 4 + w;
            GLL16(gsrc[j] + kstep * 64, &lds[buf][cl * 1024]);
        }
    };

    auto compute = [&](int buf) {
        const char* base = lds[buf];
        bf16x8 A8[2][2][2], B8[2][2][2];  // [plane][ksub][i]
#pragma unroll
        for (int p = 0; p < 2; ++p)
#pragma unroll
            for (int s = 0; s < 2; ++s)
#pragma unroll
                for (int i = 0; i < 2; ++i) {
                    A8[p][s][i] = *(const bf16x8*)(
                        base + ((p * 2 + s) * 4 + 2 * wm + i) * 1024 + lane * 16);
                    B8[p][s][i] = *(const bf16x8*)(
                        base + 16384 +
                        ((p * 2 + s) * 4 + 2 * wn + i) * 1024 + lane * 16);
                }
#pragma unroll
        for (int s = 0; s < 2; ++s)
#pragma unroll
            for (int mi = 0; mi < 2; ++mi)
#pragma unroll
                for (int ni = 0; ni < 2; ++ni) {
                    acc[mi][ni] = __builtin_amdgcn_mfma_f32_16x16x32_bf16(
                        A8[0][s][mi], B8[0][s][ni], acc[mi][ni], 0, 0, 0);
                    acc[mi][ni] = __builtin_amdgcn_mfma_f32_16x16x32_bf16(
                        A8[0][s][mi], B8[1][s][ni], acc[mi][ni], 0, 0, 0);
                    acc[mi][ni] = __builtin_amdgcn_mfma_f32_16x16x32_bf16(
                        A8[1][s][mi], B8[0][s][ni], acc[mi][ni], 0, 0, 0);
                }
    };

    const int nsteps = Kdim >> 6;  // 8
    stage(0, 0);
    asm volatile("s_waitcnt vmcnt(0)" ::: "memory");
    __syncthreads();
    for (int ks = 0; ks < nsteps - 1; ++ks) {
        stage((ks + 1) & 1, ks + 1);  // prefetch next K-tile
        compute(ks & 1);
        asm volatile("s_waitcnt vmcnt(0)" ::: "memory");
        __syncthreads();
    }
    compute((nsteps - 1) & 1);

#pragma unroll
    for (int mi = 0; mi < 2; ++mi)
#pragma unroll
        for (int ni = 0; ni < 2; ++ni)
#pragma unroll
            for (int rr = 0; rr < 4; ++rr)
                C[(size_t)(m0 + 32 * wm + 16 * mi + qd * 4 + rr) * Ndim +
                  n0 + 32 * wn + 16 * ni + r] = acc[mi][ni][rr];
}

// ---------------------------------------------------------------------------
// Attention: one wave per (b,h,i) query. float4 gather: lane l = 16*grp+sub
// loads 16B of row (4g+grp); one wave-load fetches 4 rows (1KB).
//
// CHANGE vs prior: NO row-0 redirect for masked entries. knn_idx is always a
// valid row, and masked K values never reach the output (logit forced to
// -FLT_MAX), so we gather the REAL row for both K and V unconditionally.
// The old redirect funneled ~1M line-requests at one 256B address; with the
// random gather stream thrashing L1, those serialized on a single L2 slice.
// Side benefits: K+V of a row are now one contiguous 512B read; the
// ballot/allmasked logic disappears (all-masked -> all logits equal ->
// uniform 1/32 over real V rows, identical to the jax reference).
// ---------------------------------------------------------------------------
__global__ __launch_bounds__(256) void attn_kernel(
    const float* __restrict__ qbuf,       // [b*n][512] fp32
    const float* __restrict__ mem_db,     // [b][M][128]
    const int* __restrict__ knn_idx,      // [b][h][n][K]
    const void* __restrict__ mem_mask,    // [b][h][n][K] bool-or-int32
    const float* __restrict__ scale_param,// [h]
    const int* __restrict__ flag,
    unsigned short* __restrict__ out_hi,  // [b*n][512] bf16 hi plane
    unsigned short* __restrict__ out_lo)  // [b*n][512] bf16 lo plane
{
    const int wave = blockIdx.x * 4 + (threadIdx.x >> 6);
    const int lane = threadIdx.x & 63;
    const int sub = lane & 15, grp = lane >> 4;
    const int i = wave % N_SEQ;
    const int bh = wave / N_SEQ;
    const int hi = bh % H_HEADS;
    const int bi = bh / H_HEADS;

    const int bytelayout = *flag;  // uniform

    // Issue index/mask loads first so they overlap the q phase.
    const size_t kb = ((size_t)(bi * H_HEADS + hi) * N_SEQ + i) * K_NN;
    int idxv = 0, maskv = 0;
    if (lane < K_NN) {
        idxv = knn_idx[kb + lane];
        if (bytelayout)
            maskv = ((const unsigned char*)mem_mask)[kb + lane] ? 1 : 0;
        else
            maskv = ((const int*)mem_mask)[kb + lane] ? 1 : 0;
    }

    const float* dbb = mem_db + (size_t)bi * M_DB * (2 * D_HEAD);

    // Gather: group g covers rows 4g..4g+3; my row = 4g+grp, my 16B = [4*sub..]
    // Real row always; K and V halves are adjacent 256B of the same 512B row.
    float4 kk[8], vv[8];
#pragma unroll
    for (int g = 0; g < 8; ++g) {
        int idx = __shfl(idxv, 4 * g + grp);
        const float* rowp = dbb + (size_t)idx * (2 * D_HEAD) + 4 * sub;
        kk[g] = *(const float4*)(rowp);
        vv[g] = *(const float4*)(rowp + D_HEAD);
    }

    const float* qrow = qbuf + (size_t)(bi * N_SEQ + i) * DIM + hi * D_HEAD;
    float qv = qrow[lane];
    float ss = qv * qv;
#pragma unroll
    for (int s = 32; s; s >>= 1) ss += __shfl_xor(ss, s);
    qv = qv / fmaxf(sqrtf(ss), 1e-12f);

    // q in float4-per-lane layout: q4[c] = q[4*sub + c]
    float q4[4];
#pragma unroll
    for (int c = 0; c < 4; ++c) q4[c] = __shfl(qv, 4 * sub + c);

    const float scale = __expf(scale_param[hi]);

    // Dot products: 4-elem partial per lane, 4-step butterfly over 16 lanes
    float s8[8];
#pragma unroll
    for (int g = 0; g < 8; ++g) {
        float p = q4[0] * kk[g].x + q4[1] * kk[g].y + q4[2] * kk[g].z + q4[3] * kk[g].w;
        p += __shfl_xor(p, 1);
        p += __shfl_xor(p, 2);
        p += __shfl_xor(p, 4);
        p += __shfl_xor(p, 8);
        s8[g] = p;  // full dot of row 4g+grp (replicated in 16-lane group)
    }

    // Collect: lane j<32 takes s8[j>>2] from source lane (j&3)<<4
    float simlane = -INFINITY;
#pragma unroll
    for (int g = 0; g < 8; ++g) {
        float tv = __shfl(s8[g], (lane & 3) << 4);
        if ((lane >> 2) == g) simlane = tv;  // lanes>=32 never match: stay -inf
    }
    if (lane < K_NN)
        simlane = maskv ? simlane * scale : -3.402823466e38f;

    // Softmax across 64 lanes
    float m = simlane;
#pragma unroll
    for (int s = 32; s; s >>= 1) m = fmaxf(m, __shfl_xor(m, s));
    float w = __expf(simlane - m);
    float l = w;
#pragma unroll
    for (int s = 32; s; s >>= 1) l += __shfl_xor(l, s);
    float winv = w / l;

    // Weighted sum of V (float4 layout), then reduce across the 4 groups
    float4 o = {0.f, 0.f, 0.f, 0.f};
#pragma unroll
    for (int g = 0; g < 8; ++g) {
        float wg = __shfl(winv, 4 * g + grp);
        o.x = fmaf(wg, vv[g].x, o.x);
        o.y = fmaf(wg, vv[g].y, o.y);
        o.z = fmaf(wg, vv[g].z, o.z);
        o.w = fmaf(wg, vv[g].w, o.w);
    }
#pragma unroll
    for (int s = 16; s <= 32; s <<= 1) {
        o.x += __shfl_xor(o.x, s);
        o.y += __shfl_xor(o.y, s);
        o.z += __shfl_xor(o.z, s);
        o.w += __shfl_xor(o.w, s);
    }
    if (grp == 0) {
        ushort4 h, l4;
        split4(o, h, l4);
        size_t off = ((size_t)(bi * N_SEQ + i) * DIM + hi * D_HEAD + 4 * sub) >> 2;
        ((ushort4*)out_hi)[off] = h;
        ((ushort4*)out_lo)[off] = l4;
    }
}

// ---------------------------------------------------------------------------
extern "C" void kernel_launch(void* const* d_in, const int* in_sizes, int n_in,
                              void* d_out, int out_size, void* d_ws, size_t ws_size,
                              hipStream_t stream) {
    const float* x        = (const float*)d_in[0];
    const float* mem_db   = (const float*)d_in[1];
    const int*   knn_idx  = (const int*)d_in[2];
    const void*  mem_mask = d_in[3];
    const float* Wq       = (const float*)d_in[4];
    // d_in[5] = Wkv: dead code in the reference, unused.
    const float* Wout     = (const float*)d_in[6];
    const float* scale_p  = (const float*)d_in[7];
    float* out = (float*)d_out;

    const int Mrows = B_SZ * N_SEQ;  // 4096
    const int n_x   = Mrows * DIM;   // 2097152
    const int n_w   = DIM * DIM;     // 262144

    // Workspace: flag | qbuf fp32 (8MB) | x planes (8MB) | ao planes (8MB)
    //            | 4 weight planes (2MB)   -> ~26.3 MB total
    char* ws = (char*)d_ws;
    int* flag = (int*)ws;
    float* qbuf = (float*)(ws + 256);
    unsigned short* x_hi  = (unsigned short*)(qbuf + (size_t)n_x);
    unsigned short* x_lo  = x_hi + n_x;
    unsigned short* ao_hi = x_lo + n_x;
    unsigned short* ao_lo = ao_hi + n_x;
    unsigned short* wq_hi = ao_lo + n_x;
    unsigned short* wq_lo = wq_hi + n_w;
    unsigned short* wo_hi = wq_lo + n_w;
    unsigned short* wo_lo = wo_hi + n_w;

    prep_kernel<<<2561, 256, 0, stream>>>(
        (const float4*)x, (const float4*)Wq, (const float4*)Wout,
        (ushort4*)x_hi, (ushort4*)x_lo,
        (ushort4*)wq_hi, (ushort4*)wq_lo, (ushort4*)wo_hi, (ushort4*)wo_lo,
        (const unsigned char*)mem_mask, flag);

    dim3 ggrid(Mrows / 64, DIM / 64);  // (64, 8) = 512 blocks = 2/CU
    gemm_mfma_lds<<<ggrid, 256, 0, stream>>>(x_hi, x_lo, wq_hi, wq_lo, qbuf,
                                             Mrows, DIM, DIM);

    const int n_waves = B_SZ * H_HEADS * N_SEQ;  // 32768
    attn_kernel<<<n_waves / 4, 256, 0, stream>>>(qbuf, mem_db, knn_idx, mem_mask,
                                                 scale_p, flag, ao_hi, ao_lo);

    gemm_mfma_lds<<<ggrid, 256, 0, stream>>>(ao_hi, ao_lo, wo_hi, wo_lo, out,
                                             Mrows, DIM, DIM);
}

// Round 4
// 278.228 us; speedup vs baseline: 1.0112x; 1.0112x over previous
//
#include <hip/hip_runtime.h>
#include <hip/hip_bf16.h>
#include <math.h>

// Problem constants (fixed by setup_inputs)
#define B_SZ 2
#define N_SEQ 2048
#define DIM 512
#define H_HEADS 8
#define D_HEAD 64
#define K_NN 32
#define M_DB 131072

typedef __attribute__((ext_vector_type(8))) short bf16x8;
typedef __attribute__((ext_vector_type(4))) float f32x4;

// async global->LDS, 16B per lane. LDS dest is wave-uniform base + lane*16;
// global src is per-lane (pre-swizzle the SOURCE, keep LDS linear).
#define GLL16(g, l)                                                       \
    __builtin_amdgcn_global_load_lds(                                     \
        (const __attribute__((address_space(1))) unsigned int*)(g),       \
        (__attribute__((address_space(3))) unsigned int*)(l), 16, 0, 0)

// ---------------------------------------------------------------------------
// fp32 -> (hi, lo) bf16 split. f ~= hi + lo to ~2^-17 relative.
// ---------------------------------------------------------------------------
__device__ __forceinline__ void cvt_hi_lo(float f, short& h, short& l) {
    unsigned u = __float_as_uint(f);
    unsigned uh = u + (0x7fffu + ((u >> 16) & 1u));
    h = (short)(uh >> 16);
    float r = f - __uint_as_float((uh >> 16) << 16);
    unsigned ur = __float_as_uint(r);
    l = (short)((ur + (0x7fffu + ((ur >> 16) & 1u))) >> 16);
}

__device__ __forceinline__ void split4(float4 a, ushort4& h, ushort4& l) {
    short hh, ll;
    cvt_hi_lo(a.x, hh, ll); h.x = hh; l.x = ll;
    cvt_hi_lo(a.y, hh, ll); h.y = hh; l.y = ll;
    cvt_hi_lo(a.z, hh, ll); h.z = hh; l.z = ll;
    cvt_hi_lo(a.w, hh, ll); h.w = hh; l.w = ll;
}

// ---------------------------------------------------------------------------
// Fused prep: split x (2048 blocks) + Wq/Wout (512 blocks) into bf16 hi/lo
// planes, and detect mask layout (1 block). One dispatch.
// ---------------------------------------------------------------------------
__global__ __launch_bounds__(256) void prep_kernel(
    const float4* __restrict__ x, const float4* __restrict__ wq,
    const float4* __restrict__ wout,
    ushort4* __restrict__ xhi, ushort4* __restrict__ xlo,
    ushort4* __restrict__ qhi, ushort4* __restrict__ qlo,
    ushort4* __restrict__ ohi, ushort4* __restrict__ olo,
    const unsigned char* __restrict__ mb, int* __restrict__ flag)
{
    const int bid = blockIdx.x;
    const int t = threadIdx.x;
    if (bid < 2048) {                       // x: 524288 float4s
        int i = bid * 256 + t;
        ushort4 h, l;
        split4(x[i], h, l);
        xhi[i] = h; xlo[i] = l;
    } else if (bid < 2560) {                // weights: 2*65536 float4s
        int i = (bid - 2048) * 256 + t;
        const int n4 = DIM * DIM / 4;       // 65536
        const float4* src = (i < n4) ? wq : wout;
        ushort4* dh = (i < n4) ? qhi : ohi;
        ushort4* dl = (i < n4) ? qlo : olo;
        int j = (i < n4) ? i : i - n4;
        ushort4 h, l;
        split4(src[j], h, l);
        dh[j] = h; dl[j] = l;
    } else {                                // mask-layout detect (64 lanes act)
        if (t < 64) {
            unsigned char v = 0;
            for (int e = t; e < 1024; e += 64) {
                v |= mb[4 * e + 1];
                v |= mb[4 * e + 2];
                v |= mb[4 * e + 3];
            }
            unsigned long long any = __ballot(v != 0);
            if (t == 0) *flag = (any != 0ull) ? 1 : 0;  // 1 = byte layout
        }
    }
}

// ---------------------------------------------------------------------------
// fp32-accurate MFMA GEMM (NT) on pre-split bf16 planes, LDS-STAGED:
// C[m,n] = sum_k A[m,k]*W[n,k], 3 passes (hh + hl + lh) ~= fp32.
//
// Tile 32(M) x 64(N), BK=64 — halved from 64x64 so grid = (128,8) = 1024
// blocks = 3 blocks/CU resident (old 512 = 2/CU was the occupancy limiter;
// the per-kstep vmcnt(0)+barrier drain had too little co-resident MFMA to
// hide under). LDS 2 x 24KB.
//
// Fragment-order staging (as before): global_load_lds writes LDS linearly
// (base+lane*16); the GLOBAL source is pre-swizzled so each 1KB chunk lands
// as one MFMA fragment-set. Chunks 0..7 = A (p=plane, s=k-half, i=16-row
// half): cl=(p*2+s)*2+i. Chunks 8..23 = B (p,s, h=16-row group):
// cl=8+(p*2+s)*4+h. Lane l stages row 16*{i,h}+(l&15), cols 32s+8*(l>>4)..+7.
// Compute read = chunk*1024 + lane*16: linear, conflict-free.
//
// Block: 256 thr = 4 waves; wave w computes 32x16 (n-slice 16*w) = 2x1 of
// 16x16x32 mfma, 12 MFMA/kstep.
// A-frag: m=lane&15, k=(lane>>4)*8+j.  C/D: col=lane&15, row=(lane>>4)*4+reg.
// ---------------------------------------------------------------------------
__global__ __launch_bounds__(256) void gemm_mfma_lds(
    const unsigned short* __restrict__ Ahi, const unsigned short* __restrict__ Alo,
    const unsigned short* __restrict__ Bhi, const unsigned short* __restrict__ Blo,
    float* __restrict__ C, int Mdim, int Ndim, int Kdim)
{
    __shared__ char lds[2][24576];
    const int t = threadIdx.x;
    const int w = t >> 6, lane = t & 63;
    const int r = lane & 15, qd = lane >> 4;
    const int m0 = blockIdx.x * 32;
    const int n0 = blockIdx.y * 64;

    // Per-wave staging sources: 6 chunks (cl = j*4 + w), kstep-0 addresses.
    const unsigned short* gsrc[6];
#pragma unroll
    for (int j = 0; j < 6; ++j) {
        const int cl = j * 4 + w;
        int row, col;
        const unsigned short* plane;
        if (cl < 8) {                       // A chunk
            const int p = cl >> 2, s = (cl >> 1) & 1, i = cl & 1;
            row = m0 + 16 * i + r;
            col = 32 * s + 8 * qd;
            plane = p ? Alo : Ahi;
        } else {                            // B chunk
            const int c = cl - 8;
            const int p = c >> 3, s = (c >> 2) & 1, h = c & 3;
            row = n0 + 16 * h + r;
            col = 32 * s + 8 * qd;
            plane = p ? Blo : Bhi;
        }
        gsrc[j] = plane + (size_t)row * Kdim + col;
    }

    f32x4 acc[2];
    acc[0] = (f32x4){0.f, 0.f, 0.f, 0.f};
    acc[1] = (f32x4){0.f, 0.f, 0.f, 0.f};

    auto stage = [&](int buf, int kstep) {
#pragma unroll
        for (int j = 0; j < 6; ++j) {
            const int cl = j * 4 + w;
            GLL16(gsrc[j] + kstep * 64, &lds[buf][cl * 1024]);
        }
    };

    auto compute = [&](int buf) {
        const char* base = lds[buf];
        bf16x8 A8[2][2][2], B8[2][2];  // A[p][s][i], B[p][s] (this wave's h=w)
#pragma unroll
        for (int p = 0; p < 2; ++p)
#pragma unroll
            for (int s = 0; s < 2; ++s) {
#pragma unroll
                for (int i = 0; i < 2; ++i)
                    A8[p][s][i] = *(const bf16x8*)(
                        base + ((p * 2 + s) * 2 + i) * 1024 + lane * 16);
                B8[p][s] = *(const bf16x8*)(
                    base + 8192 + ((p * 2 + s) * 4 + w) * 1024 + lane * 16);
            }
#pragma unroll
        for (int s = 0; s < 2; ++s)
#pragma unroll
            for (int mi = 0; mi < 2; ++mi) {
                acc[mi] = __builtin_amdgcn_mfma_f32_16x16x32_bf16(
                    A8[0][s][mi], B8[0][s], acc[mi], 0, 0, 0);
                acc[mi] = __builtin_amdgcn_mfma_f32_16x16x32_bf16(
                    A8[0][s][mi], B8[1][s], acc[mi], 0, 0, 0);
                acc[mi] = __builtin_amdgcn_mfma_f32_16x16x32_bf16(
                    A8[1][s][mi], B8[0][s], acc[mi], 0, 0, 0);
            }
    };

    const int nsteps = Kdim >> 6;  // 8
    stage(0, 0);
    asm volatile("s_waitcnt vmcnt(0)" ::: "memory");
    __syncthreads();
    for (int ks = 0; ks < nsteps - 1; ++ks) {
        stage((ks + 1) & 1, ks + 1);  // prefetch next K-tile
        compute(ks & 1);
        asm volatile("s_waitcnt vmcnt(0)" ::: "memory");
        __syncthreads();
    }
    compute((nsteps - 1) & 1);

#pragma unroll
    for (int mi = 0; mi < 2; ++mi)
#pragma unroll
        for (int rr = 0; rr < 4; ++rr)
            C[(size_t)(m0 + 16 * mi + qd * 4 + rr) * Ndim + n0 + 16 * w + r] =
                acc[mi][rr];
}

// ---------------------------------------------------------------------------
// Attention: one wave per (b,h,i) query. float4 gather: lane l = 16*grp+sub
// loads 16B of row (4g+grp); one wave-load fetches 4 rows (1KB).
//
// Row-0 redirect RESTORED (round-3 counters: real-row-always doubled FETCH
// to 254MB and cost +18us — row 0 is cache-resident and serves ~50% of
// gathers for free; attn is bytes-bound at the ~3TB/s random-gather ceiling).
// Masked rows -> row 0; garbage annihilated by -FLT_MAX / zero weight;
// all-masked case uses real v addresses -> jax uniform 1/32. Kept from
// round 3: idx/mask loads issued BEFORE the q phase so their latency hides
// under q-norm. Output written as pre-split bf16 hi/lo planes.
// ---------------------------------------------------------------------------
__global__ __launch_bounds__(256) void attn_kernel(
    const float* __restrict__ qbuf,       // [b*n][512] fp32
    const float* __restrict__ mem_db,     // [b][M][128]
    const int* __restrict__ knn_idx,      // [b][h][n][K]
    const void* __restrict__ mem_mask,    // [b][h][n][K] bool-or-int32
    const float* __restrict__ scale_param,// [h]
    const int* __restrict__ flag,
    unsigned short* __restrict__ out_hi,  // [b*n][512] bf16 hi plane
    unsigned short* __restrict__ out_lo)  // [b*n][512] bf16 lo plane
{
    const int wave = blockIdx.x * 4 + (threadIdx.x >> 6);
    const int lane = threadIdx.x & 63;
    const int sub = lane & 15, grp = lane >> 4;
    const int i = wave % N_SEQ;
    const int bh = wave / N_SEQ;
    const int hi = bh % H_HEADS;
    const int bi = bh / H_HEADS;

    const int bytelayout = *flag;  // uniform

    // Issue index/mask loads first so they overlap the q phase.
    const size_t kb = ((size_t)(bi * H_HEADS + hi) * N_SEQ + i) * K_NN;
    int idxv = 0, maskv = 0;
    if (lane < K_NN) {
        idxv = knn_idx[kb + lane];
        if (bytelayout)
            maskv = ((const unsigned char*)mem_mask)[kb + lane] ? 1 : 0;
        else
            maskv = ((const int*)mem_mask)[kb + lane] ? 1 : 0;
    }

    const float* qrow = qbuf + (size_t)(bi * N_SEQ + i) * DIM + hi * D_HEAD;
    float qv = qrow[lane];
    float ss = qv * qv;
#pragma unroll
    for (int s = 32; s; s >>= 1) ss += __shfl_xor(ss, s);
    qv = qv / fmaxf(sqrtf(ss), 1e-12f);

    // q in float4-per-lane layout: q4[c] = q[4*sub + c]
    float q4[4];
#pragma unroll
    for (int c = 0; c < 4; ++c) q4[c] = __shfl(qv, 4 * sub + c);

    const float scale = __expf(scale_param[hi]);

    unsigned long long mbits = __ballot(maskv != 0);
    const bool allmasked = (mbits == 0ull);

    const float* dbb = mem_db + (size_t)bi * M_DB * (2 * D_HEAD);

    // Gather: group g covers rows 4g..4g+3; my row = 4g+grp, my 16B = [4*sub..]
    float4 kk[8], vv[8];
#pragma unroll
    for (int g = 0; g < 8; ++g) {
        int idx = __shfl(idxv, 4 * g + grp);
        bool mrow = (mbits >> (4 * g + grp)) & 1ull;
        size_t koff = mrow ? (size_t)idx * (2 * D_HEAD) : 0;
        size_t voff = (mrow || allmasked) ? (size_t)idx * (2 * D_HEAD) : 0;
        kk[g] = *(const float4*)(dbb + koff + 4 * sub);
        vv[g] = *(const float4*)(dbb + voff + D_HEAD + 4 * sub);
    }

    // Dot products: 4-elem partial per lane, 4-step butterfly over 16 lanes
    float s8[8];
#pragma unroll
    for (int g = 0; g < 8; ++g) {
        float p = q4[0] * kk[g].x + q4[1] * kk[g].y + q4[2] * kk[g].z + q4[3] * kk[g].w;
        p += __shfl_xor(p, 1);
        p += __shfl_xor(p, 2);
        p += __shfl_xor(p, 4);
        p += __shfl_xor(p, 8);
        s8[g] = p;  // full dot of row 4g+grp (replicated in 16-lane group)
    }

    // Collect: lane j<32 takes s8[j>>2] from source lane (j&3)<<4
    float simlane = -INFINITY;
#pragma unroll
    for (int g = 0; g < 8; ++g) {
        float tv = __shfl(s8[g], (lane & 3) << 4);
        if ((lane >> 2) == g) simlane = tv;  // lanes>=32 never match: stay -inf
    }
    if (lane < K_NN)
        simlane = maskv ? simlane * scale : -3.402823466e38f;

    // Softmax across 64 lanes
    float m = simlane;
#pragma unroll
    for (int s = 32; s; s >>= 1) m = fmaxf(m, __shfl_xor(m, s));
    float w = __expf(simlane - m);
    float l = w;
#pragma unroll
    for (int s = 32; s; s >>= 1) l += __shfl_xor(l, s);
    float winv = w / l;

    // Weighted sum of V (float4 layout), then reduce across the 4 groups
    float4 o = {0.f, 0.f, 0.f, 0.f};
#pragma unroll
    for (int g = 0; g < 8; ++g) {
        float wg = __shfl(winv, 4 * g + grp);
        o.x = fmaf(wg, vv[g].x, o.x);
        o.y = fmaf(wg, vv[g].y, o.y);
        o.z = fmaf(wg, vv[g].z, o.z);
        o.w = fmaf(wg, vv[g].w, o.w);
    }
#pragma unroll
    for (int s = 16; s <= 32; s <<= 1) {
        o.x += __shfl_xor(o.x, s);
        o.y += __shfl_xor(o.y, s);
        o.z += __shfl_xor(o.z, s);
        o.w += __shfl_xor(o.w, s);
    }
    if (grp == 0) {
        ushort4 h, l4;
        split4(o, h, l4);
        size_t off = ((size_t)(bi * N_SEQ + i) * DIM + hi * D_HEAD + 4 * sub) >> 2;
        ((ushort4*)out_hi)[off] = h;
        ((ushort4*)out_lo)[off] = l4;
    }
}

// ---------------------------------------------------------------------------
extern "C" void kernel_launch(void* const* d_in, const int* in_sizes, int n_in,
                              void* d_out, int out_size, void* d_ws, size_t ws_size,
                              hipStream_t stream) {
    const float* x        = (const float*)d_in[0];
    const float* mem_db   = (const float*)d_in[1];
    const int*   knn_idx  = (const int*)d_in[2];
    const void*  mem_mask = d_in[3];
    const float* Wq       = (const float*)d_in[4];
    // d_in[5] = Wkv: dead code in the reference, unused.
    const float* Wout     = (const float*)d_in[6];
    const float* scale_p  = (const float*)d_in[7];
    float* out = (float*)d_out;

    const int Mrows = B_SZ * N_SEQ;  // 4096
    const int n_x   = Mrows * DIM;   // 2097152
    const int n_w   = DIM * DIM;     // 262144

    // Workspace: flag | qbuf fp32 (8MB) | x planes (8MB) | ao planes (8MB)
    //            | 4 weight planes (2MB)   -> ~26.3 MB total
    char* ws = (char*)d_ws;
    int* flag = (int*)ws;
    float* qbuf = (float*)(ws + 256);
    unsigned short* x_hi  = (unsigned short*)(qbuf + (size_t)n_x);
    unsigned short* x_lo  = x_hi + n_x;
    unsigned short* ao_hi = x_lo + n_x;
    unsigned short* ao_lo = ao_hi + n_x;
    unsigned short* wq_hi = ao_lo + n_x;
    unsigned short* wq_lo = wq_hi + n_w;
    unsigned short* wo_hi = wq_lo + n_w;
    unsigned short* wo_lo = wo_hi + n_w;

    prep_kernel<<<2561, 256, 0, stream>>>(
        (const float4*)x, (const float4*)Wq, (const float4*)Wout,
        (ushort4*)x_hi, (ushort4*)x_lo,
        (ushort4*)wq_hi, (ushort4*)wq_lo, (ushort4*)wo_hi, (ushort4*)wo_lo,
        (const unsigned char*)mem_mask, flag);

    dim3 ggrid(Mrows / 32, DIM / 64);  // (128, 8) = 1024 blocks = 3/CU
    gemm_mfma_lds<<<ggrid, 256, 0, stream>>>(x_hi, x_lo, wq_hi, wq_lo, qbuf,
                                             Mrows, DIM, DIM);

    const int n_waves = B_SZ * H_HEADS * N_SEQ;  // 32768
    attn_kernel<<<n_waves / 4, 256, 0, stream>>>(qbuf, mem_db, knn_idx, mem_mask,
                                                 scale_p, flag, ao_hi, ao_lo);

    gemm_mfma_lds<<<ggrid, 256, 0, stream>>>(ao_hi, ao_lo, wo_hi, wo_lo, out,
                                             Mrows, DIM, DIM);
}

// Round 5
// 261.085 us; speedup vs baseline: 1.0776x; 1.0657x over previous
//
#include <hip/hip_runtime.h>
#include <hip/hip_bf16.h>
#include <math.h>

// Problem constants (fixed by setup_inputs)
#define B_SZ 2
#define N_SEQ 2048
#define DIM 512
#define H_HEADS 8
#define D_HEAD 64
#define K_NN 32
#define M_DB 131072

typedef __attribute__((ext_vector_type(8))) short bf16x8;
typedef __attribute__((ext_vector_type(4))) float f32x4;

// async global->LDS, 16B per lane. LDS dest is wave-uniform base + lane*16;
// global src is per-lane (pre-swizzle the SOURCE, keep LDS linear).
#define GLL16(g, l)                                                       \
    __builtin_amdgcn_global_load_lds(                                     \
        (const __attribute__((address_space(1))) unsigned int*)(g),       \
        (__attribute__((address_space(3))) unsigned int*)(l), 16, 0, 0)

// ---------------------------------------------------------------------------
// fp32 -> (hi, lo) bf16 split. f ~= hi + lo to ~2^-17 relative.
// ---------------------------------------------------------------------------
__device__ __forceinline__ void cvt_hi_lo(float f, short& h, short& l) {
    unsigned u = __float_as_uint(f);
    unsigned uh = u + (0x7fffu + ((u >> 16) & 1u));
    h = (short)(uh >> 16);
    float r = f - __uint_as_float((uh >> 16) << 16);
    unsigned ur = __float_as_uint(r);
    l = (short)((ur + (0x7fffu + ((ur >> 16) & 1u))) >> 16);
}

__device__ __forceinline__ void split4(float4 a, ushort4& h, ushort4& l) {
    short hh, ll;
    cvt_hi_lo(a.x, hh, ll); h.x = hh; l.x = ll;
    cvt_hi_lo(a.y, hh, ll); h.y = hh; l.y = ll;
    cvt_hi_lo(a.z, hh, ll); h.z = hh; l.z = ll;
    cvt_hi_lo(a.w, hh, ll); h.w = hh; l.w = ll;
}

// ---------------------------------------------------------------------------
// Fused prep: split x (2048 blocks) + Wq/Wout (512 blocks) into bf16 hi/lo
// planes, and detect mask layout (1 block). One dispatch.
// ---------------------------------------------------------------------------
__global__ __launch_bounds__(256) void prep_kernel(
    const float4* __restrict__ x, const float4* __restrict__ wq,
    const float4* __restrict__ wout,
    ushort4* __restrict__ xhi, ushort4* __restrict__ xlo,
    ushort4* __restrict__ qhi, ushort4* __restrict__ qlo,
    ushort4* __restrict__ ohi, ushort4* __restrict__ olo,
    const unsigned char* __restrict__ mb, int* __restrict__ flag)
{
    const int bid = blockIdx.x;
    const int t = threadIdx.x;
    if (bid < 2048) {                       // x: 524288 float4s
        int i = bid * 256 + t;
        ushort4 h, l;
        split4(x[i], h, l);
        xhi[i] = h; xlo[i] = l;
    } else if (bid < 2560) {                // weights: 2*65536 float4s
        int i = (bid - 2048) * 256 + t;
        const int n4 = DIM * DIM / 4;       // 65536
        const float4* src = (i < n4) ? wq : wout;
        ushort4* dh = (i < n4) ? qhi : ohi;
        ushort4* dl = (i < n4) ? qlo : olo;
        int j = (i < n4) ? i : i - n4;
        ushort4 h, l;
        split4(src[j], h, l);
        dh[j] = h; dl[j] = l;
    } else {                                // mask-layout detect (64 lanes act)
        if (t < 64) {
            unsigned char v = 0;
            for (int e = t; e < 1024; e += 64) {
                v |= mb[4 * e + 1];
                v |= mb[4 * e + 2];
                v |= mb[4 * e + 3];
            }
            unsigned long long any = __ballot(v != 0);
            if (t == 0) *flag = (any != 0ull) ? 1 : 0;  // 1 = byte layout
        }
    }
}

// ---------------------------------------------------------------------------
// fp32-accurate MFMA GEMM (NT) on pre-split bf16 planes, LDS-STAGED with a
// 2-DEEP counted-vmcnt pipeline:
// C[m,n] = sum_k A[m,k]*W[n,k], 3 passes (hh + hl + lh) ~= fp32.
//
// Round-4 lesson: 32x64 tile regressed (1.5x staging bytes, half the MFMA
// per drain) -> tile stays 64x64. The real cost is the per-kstep vmcnt(0)
// drain: compute is ~60cyc of MFMA but the drain waits ~300-600cyc for the
// just-issued prefetch. Fix = depth: BK=32, THREE 16KB buffers, prefetch
// 2 tiles ahead, wait s_waitcnt vmcnt(4) (tile k done, k+1 still in
// flight), raw s_barrier (NOT __syncthreads, which drains vmcnt to 0).
// Per-wave per-kstep: 4 global_load_lds + 8 ds_read_b128 + 12 MFMA.
// Accumulation order is bit-identical to the round-2 BK=64 version.
//
// Fragment-order staging: chunk c(0..7)=A: p=c>>2 (plane), h=c&3 (16-row
// group); c(8..15)=B likewise. Lane l stages row 16h+(l&15), cols
// 8*(l>>4)..+7 of the BK=32 slice. Compute read = chunk*1024 + lane*16:
// linear, conflict-free.
//
// Block: 256 thr = 4 waves; wave = 32x32 out = 2x2 of 16x16x32 mfma.
// A-frag: m=lane&15, k=(lane>>4)*8+j.  C/D: col=lane&15, row=(lane>>4)*4+reg.
// ---------------------------------------------------------------------------
__global__ __launch_bounds__(256) void gemm_mfma_lds(
    const unsigned short* __restrict__ Ahi, const unsigned short* __restrict__ Alo,
    const unsigned short* __restrict__ Bhi, const unsigned short* __restrict__ Blo,
    float* __restrict__ C, int Mdim, int Ndim, int Kdim)
{
    __shared__ char lds[3][16384];
    const int t = threadIdx.x;
    const int w = t >> 6, lane = t & 63;
    const int r = lane & 15, qd = lane >> 4;
    const int wm = w & 1, wn = w >> 1;
    const int m0 = blockIdx.x * 64;
    const int n0 = blockIdx.y * 64;

    // Per-wave staging sources: 4 chunks (cl = j*4 + w), kstep-0 addresses.
    const unsigned short* gsrc[4];
#pragma unroll
    for (int j = 0; j < 4; ++j) {
        const int cl = j * 4 + w;
        const int isB = cl >> 3;
        const int c = cl & 7;
        const int p = c >> 2, h = c & 3;
        const int row = (isB ? n0 : m0) + 16 * h + r;
        const unsigned short* plane =
            isB ? (p ? Blo : Bhi) : (p ? Alo : Ahi);
        gsrc[j] = plane + (size_t)row * Kdim + 8 * qd;
    }

    f32x4 acc[2][2];
#pragma unroll
    for (int i = 0; i < 2; ++i)
#pragma unroll
        for (int j = 0; j < 2; ++j) acc[i][j] = (f32x4){0.f, 0.f, 0.f, 0.f};

    auto stage = [&](int buf, int kstep) {
#pragma unroll
        for (int j = 0; j < 4; ++j) {
            const int cl = j * 4 + w;
            GLL16(gsrc[j] + kstep * 32, &lds[buf][cl * 1024]);
        }
    };

    auto compute = [&](int buf) {
        const char* base = lds[buf];
        bf16x8 A8[2][2], B8[2][2];  // [plane][i]
#pragma unroll
        for (int p = 0; p < 2; ++p)
#pragma unroll
            for (int i = 0; i < 2; ++i) {
                A8[p][i] = *(const bf16x8*)(
                    base + (p * 4 + 2 * wm + i) * 1024 + lane * 16);
                B8[p][i] = *(const bf16x8*)(
                    base + 8192 + (p * 4 + 2 * wn + i) * 1024 + lane * 16);
            }
#pragma unroll
        for (int mi = 0; mi < 2; ++mi)
#pragma unroll
            for (int ni = 0; ni < 2; ++ni) {
                acc[mi][ni] = __builtin_amdgcn_mfma_f32_16x16x32_bf16(
                    A8[0][mi], B8[0][ni], acc[mi][ni], 0, 0, 0);
                acc[mi][ni] = __builtin_amdgcn_mfma_f32_16x16x32_bf16(
                    A8[0][mi], B8[1][ni], acc[mi][ni], 0, 0, 0);
                acc[mi][ni] = __builtin_amdgcn_mfma_f32_16x16x32_bf16(
                    A8[1][mi], B8[0][ni], acc[mi][ni], 0, 0, 0);
            }
    };

    const int nsteps = Kdim >> 5;  // 16
    stage(0, 0);
    stage(1, 1);
    int bc = 0;  // buffer holding the current tile
    for (int ks = 0; ks < nsteps - 1; ++ks) {
        // tile ks done (its 4 loads are the oldest); tile ks+1's 4 may fly on
        asm volatile("s_waitcnt vmcnt(4)" ::: "memory");
        __builtin_amdgcn_s_barrier();
        if (ks + 2 < nsteps) {
            int bs = bc + 2; if (bs >= 3) bs -= 3;
            stage(bs, ks + 2);
        }
        compute(bc);
        if (++bc == 3) bc = 0;
    }
    asm volatile("s_waitcnt vmcnt(0)" ::: "memory");
    __builtin_amdgcn_s_barrier();
    compute(bc);

#pragma unroll
    for (int mi = 0; mi < 2; ++mi)
#pragma unroll
        for (int ni = 0; ni < 2; ++ni)
#pragma unroll
            for (int rr = 0; rr < 4; ++rr)
                C[(size_t)(m0 + 32 * wm + 16 * mi + qd * 4 + rr) * Ndim +
                  n0 + 32 * wn + 16 * ni + r] = acc[mi][ni][rr];
}

// ---------------------------------------------------------------------------
// Attention: one wave per (b,h,i) query. float4 gather: lane l = 16*grp+sub
// loads 16B of row (4g+grp); one wave-load fetches 4 rows (1KB).
//
// Row-0 redirect (round-3 counters: real-row-always doubled FETCH to 254MB
// and cost +18us — row 0 is cache-resident and serves ~50% of gathers for
// free; attn is bytes-bound at the ~3TB/s random-gather ceiling).
// Masked rows -> row 0; garbage annihilated by -FLT_MAX / zero weight;
// all-masked case uses real v addresses -> jax uniform 1/32. idx/mask loads
// issued BEFORE the q phase so their latency hides under q-norm. Output
// written as pre-split bf16 hi/lo planes.
// ---------------------------------------------------------------------------
__global__ __launch_bounds__(256) void attn_kernel(
    const float* __restrict__ qbuf,       // [b*n][512] fp32
    const float* __restrict__ mem_db,     // [b][M][128]
    const int* __restrict__ knn_idx,      // [b][h][n][K]
    const void* __restrict__ mem_mask,    // [b][h][n][K] bool-or-int32
    const float* __restrict__ scale_param,// [h]
    const int* __restrict__ flag,
    unsigned short* __restrict__ out_hi,  // [b*n][512] bf16 hi plane
    unsigned short* __restrict__ out_lo)  // [b*n][512] bf16 lo plane
{
    const int wave = blockIdx.x * 4 + (threadIdx.x >> 6);
    const int lane = threadIdx.x & 63;
    const int sub = lane & 15, grp = lane >> 4;
    const int i = wave % N_SEQ;
    const int bh = wave / N_SEQ;
    const int hi = bh % H_HEADS;
    const int bi = bh / H_HEADS;

    const int bytelayout = *flag;  // uniform

    // Issue index/mask loads first so they overlap the q phase.
    const size_t kb = ((size_t)(bi * H_HEADS + hi) * N_SEQ + i) * K_NN;
    int idxv = 0, maskv = 0;
    if (lane < K_NN) {
        idxv = knn_idx[kb + lane];
        if (bytelayout)
            maskv = ((const unsigned char*)mem_mask)[kb + lane] ? 1 : 0;
        else
            maskv = ((const int*)mem_mask)[kb + lane] ? 1 : 0;
    }

    const float* qrow = qbuf + (size_t)(bi * N_SEQ + i) * DIM + hi * D_HEAD;
    float qv = qrow[lane];
    float ss = qv * qv;
#pragma unroll
    for (int s = 32; s; s >>= 1) ss += __shfl_xor(ss, s);
    qv = qv / fmaxf(sqrtf(ss), 1e-12f);

    // q in float4-per-lane layout: q4[c] = q[4*sub + c]
    float q4[4];
#pragma unroll
    for (int c = 0; c < 4; ++c) q4[c] = __shfl(qv, 4 * sub + c);

    const float scale = __expf(scale_param[hi]);

    unsigned long long mbits = __ballot(maskv != 0);
    const bool allmasked = (mbits == 0ull);

    const float* dbb = mem_db + (size_t)bi * M_DB * (2 * D_HEAD);

    // Gather: group g covers rows 4g..4g+3; my row = 4g+grp, my 16B = [4*sub..]
    float4 kk[8], vv[8];
#pragma unroll
    for (int g = 0; g < 8; ++g) {
        int idx = __shfl(idxv, 4 * g + grp);
        bool mrow = (mbits >> (4 * g + grp)) & 1ull;
        size_t koff = mrow ? (size_t)idx * (2 * D_HEAD) : 0;
        size_t voff = (mrow || allmasked) ? (size_t)idx * (2 * D_HEAD) : 0;
        kk[g] = *(const float4*)(dbb + koff + 4 * sub);
        vv[g] = *(const float4*)(dbb + voff + D_HEAD + 4 * sub);
    }

    // Dot products: 4-elem partial per lane, 4-step butterfly over 16 lanes
    float s8[8];
#pragma unroll
    for (int g = 0; g < 8; ++g) {
        float p = q4[0] * kk[g].x + q4[1] * kk[g].y + q4[2] * kk[g].z + q4[3] * kk[g].w;
        p += __shfl_xor(p, 1);
        p += __shfl_xor(p, 2);
        p += __shfl_xor(p, 4);
        p += __shfl_xor(p, 8);
        s8[g] = p;  // full dot of row 4g+grp (replicated in 16-lane group)
    }

    // Collect: lane j<32 takes s8[j>>2] from source lane (j&3)<<4
    float simlane = -INFINITY;
#pragma unroll
    for (int g = 0; g < 8; ++g) {
        float tv = __shfl(s8[g], (lane & 3) << 4);
        if ((lane >> 2) == g) simlane = tv;  // lanes>=32 never match: stay -inf
    }
    if (lane < K_NN)
        simlane = maskv ? simlane * scale : -3.402823466e38f;

    // Softmax across 64 lanes
    float m = simlane;
#pragma unroll
    for (int s = 32; s; s >>= 1) m = fmaxf(m, __shfl_xor(m, s));
    float w = __expf(simlane - m);
    float l = w;
#pragma unroll
    for (int s = 32; s; s >>= 1) l += __shfl_xor(l, s);
    float winv = w / l;

    // Weighted sum of V (float4 layout), then reduce across the 4 groups
    float4 o = {0.f, 0.f, 0.f, 0.f};
#pragma unroll
    for (int g = 0; g < 8; ++g) {
        float wg = __shfl(winv, 4 * g + grp);
        o.x = fmaf(wg, vv[g].x, o.x);
        o.y = fmaf(wg, vv[g].y, o.y);
        o.z = fmaf(wg, vv[g].z, o.z);
        o.w = fmaf(wg, vv[g].w, o.w);
    }
#pragma unroll
    for (int s = 16; s <= 32; s <<= 1) {
        o.x += __shfl_xor(o.x, s);
        o.y += __shfl_xor(o.y, s);
        o.z += __shfl_xor(o.z, s);
        o.w += __shfl_xor(o.w, s);
    }
    if (grp == 0) {
        ushort4 h, l4;
        split4(o, h, l4);
        size_t off = ((size_t)(bi * N_SEQ + i) * DIM + hi * D_HEAD + 4 * sub) >> 2;
        ((ushort4*)out_hi)[off] = h;
        ((ushort4*)out_lo)[off] = l4;
    }
}

// ---------------------------------------------------------------------------
extern "C" void kernel_launch(void* const* d_in, const int* in_sizes, int n_in,
                              void* d_out, int out_size, void* d_ws, size_t ws_size,
                              hipStream_t stream) {
    const float* x        = (const float*)d_in[0];
    const float* mem_db   = (const float*)d_in[1];
    const int*   knn_idx  = (const int*)d_in[2];
    const void*  mem_mask = d_in[3];
    const float* Wq       = (const float*)d_in[4];
    // d_in[5] = Wkv: dead code in the reference, unused.
    const float* Wout     = (const float*)d_in[6];
    const float* scale_p  = (const float*)d_in[7];
    float* out = (float*)d_out;

    const int Mrows = B_SZ * N_SEQ;  // 4096
    const int n_x   = Mrows * DIM;   // 2097152
    const int n_w   = DIM * DIM;     // 262144

    // Workspace: flag | qbuf fp32 (8MB) | x planes (8MB) | ao planes (8MB)
    //            | 4 weight planes (2MB)   -> ~26.3 MB total
    char* ws = (char*)d_ws;
    int* flag = (int*)ws;
    float* qbuf = (float*)(ws + 256);
    unsigned short* x_hi  = (unsigned short*)(qbuf + (size_t)n_x);
    unsigned short* x_lo  = x_hi + n_x;
    unsigned short* ao_hi = x_lo + n_x;
    unsigned short* ao_lo = ao_hi + n_x;
    unsigned short* wq_hi = ao_lo + n_x;
    unsigned short* wq_lo = wq_hi + n_w;
    unsigned short* wo_hi = wq_lo + n_w;
    unsigned short* wo_lo = wo_hi + n_w;

    prep_kernel<<<2561, 256, 0, stream>>>(
        (const float4*)x, (const float4*)Wq, (const float4*)Wout,
        (ushort4*)x_hi, (ushort4*)x_lo,
        (ushort4*)wq_hi, (ushort4*)wq_lo, (ushort4*)wo_hi, (ushort4*)wo_lo,
        (const unsigned char*)mem_mask, flag);

    dim3 ggrid(Mrows / 64, DIM / 64);  // (64, 8) = 512 blocks = 2/CU
    gemm_mfma_lds<<<ggrid, 256, 0, stream>>>(x_hi, x_lo, wq_hi, wq_lo, qbuf,
                                             Mrows, DIM, DIM);

    const int n_waves = B_SZ * H_HEADS * N_SEQ;  // 32768
    attn_kernel<<<n_waves / 4, 256, 0, stream>>>(qbuf, mem_db, knn_idx, mem_mask,
                                                 scale_p, flag, ao_hi, ao_lo);

    gemm_mfma_lds<<<ggrid, 256, 0, stream>>>(ao_hi, ao_lo, wo_hi, wo_lo, out,
                                             Mrows, DIM, DIM);
}